// Round 3
// baseline (566.913 us; speedup 1.0000x reference)
//
#include <hip/hip_runtime.h>
#include <cstddef>

#define BB 2048
#define TT 200
#define HH 256
#define KK 8

// workspace layout (in floats)
#define WS_M2T  0        // 257 rows x 256 (row 256 = dvec = Wk@bq)
#define WS_EVEC 65792    // 256  (Wq@bk)
#define WS_F    66048    // 1    (bk.bq)

__device__ __forceinline__ float wred_sum(float v) {
#pragma unroll
  for (int off = 32; off; off >>= 1) v += __shfl_xor(v, off);
  return v;
}
__device__ __forceinline__ float wred_max(float v) {
#pragma unroll
  for (int off = 32; off; off >>= 1) v = fmaxf(v, __shfl_xor(v, off));
  return v;
}

// ---------------------------------------------------------------------------
// prep_all: blocks 0..15 = 64x64 tiles of M2T[l][i] = sum_j Wq[l][j]*Wk[i][j];
// blocks 16..271: M2T row 256 = Wk@bq; 272..527: evec = Wq@bk; 528: fsc = bk.bq
// ---------------------------------------------------------------------------
__global__ __launch_bounds__(256) void prep_all(
    const float* __restrict__ Wq, const float* __restrict__ bq,
    const float* __restrict__ Wk, const float* __restrict__ bk,
    float* __restrict__ M2T, float* __restrict__ evec, float* __restrict__ fsc) {
  const int tid = threadIdx.x;
  __shared__ float As[64][68], Bs[64][68];
  __shared__ float s4[4];
  if (blockIdx.x < 16) {
    const int l0 = ((int)blockIdx.x >> 2) * 64, i0 = ((int)blockIdx.x & 3) * 64;
    const int tl = tid >> 4, ti = tid & 15;
    float acc[4][4];
#pragma unroll
    for (int r = 0; r < 4; ++r)
#pragma unroll
      for (int c = 0; c < 4; ++c) acc[r][c] = 0.f;

    for (int kc = 0; kc < 4; ++kc) {
      const int k0 = kc * 64;
#pragma unroll
      for (int it = 0; it < 4; ++it) {
        int idx = it * 256 + tid;
        int row = idx >> 4, c4 = idx & 15;
        *(float4*)(&As[row][c4 * 4]) =
            *(const float4*)(Wq + (size_t)(l0 + row) * HH + k0 + c4 * 4);
        *(float4*)(&Bs[row][c4 * 4]) =
            *(const float4*)(Wk + (size_t)(i0 + row) * HH + k0 + c4 * 4);
      }
      __syncthreads();
#pragma unroll 4
      for (int k4 = 0; k4 < 16; ++k4) {
        float4 a4[4], b4[4];
#pragma unroll
        for (int r = 0; r < 4; ++r) a4[r] = *(const float4*)(&As[tl * 4 + r][k4 * 4]);
#pragma unroll
        for (int c = 0; c < 4; ++c) b4[c] = *(const float4*)(&Bs[ti * 4 + c][k4 * 4]);
#pragma unroll
        for (int r = 0; r < 4; ++r)
#pragma unroll
          for (int c = 0; c < 4; ++c)
            acc[r][c] += a4[r].x * b4[c].x + a4[r].y * b4[c].y +
                         a4[r].z * b4[c].z + a4[r].w * b4[c].w;
      }
      __syncthreads();
    }
#pragma unroll
    for (int r = 0; r < 4; ++r) {
      float4 o = make_float4(acc[r][0], acc[r][1], acc[r][2], acc[r][3]);
      *(float4*)(M2T + (size_t)(l0 + tl * 4 + r) * HH + i0 + ti * 4) = o;
    }
  } else {
    const int id = (int)blockIdx.x - 16;
    const float* row;
    const float* vec;
    float* outp;
    if (id < 256)      { row = Wk + (size_t)id * HH;         vec = bq; outp = M2T + (size_t)256 * HH + id; }
    else if (id < 512) { row = Wq + (size_t)(id - 256) * HH; vec = bk; outp = evec + (id - 256); }
    else               { row = bk;                           vec = bq; outp = fsc; }
    float p = row[tid] * vec[tid];
    p = wred_sum(p);
    if ((tid & 63) == 0) s4[tid >> 6] = p;
    __syncthreads();
    if (tid == 0) *outp = s4[0] + s4[1] + s4[2] + s4[3];
  }
}

// ---------------------------------------------------------------------------
// fused_attn2: one block per PAIR of b's (b0 = 2*blk, b1 = b0+1).
// M2T (phase 1) and Wv (phase 5) are each read ONCE per block and applied to
// both b's -> L2 traffic halves vs 1-b/block.  Top-8 runs on waves 0/1 in
// parallel.  Grid 1024 = 4 blocks/CU x 256 CU exactly (one dispatch wave).
// ---------------------------------------------------------------------------
__global__ __launch_bounds__(256, 4) void fused_attn2(
    const float* __restrict__ CS, const float* __restrict__ X,
    const int* __restrict__ VM,
    const float* __restrict__ M2T, const float* __restrict__ evec,
    const float* __restrict__ fsc,
    const float* __restrict__ Wv, const float* __restrict__ bvv,
    float* __restrict__ out) {
  const int tid = threadIdx.x;
  const int b0 = 2 * (int)blockIdx.x, b1 = b0 + 1;
  const int w = tid >> 6, lane = tid & 63;
  __shared__ float s_cs[2][HH];
  __shared__ float s_qk[2][HH];
  __shared__ float s_part[4][2][HH];
  __shared__ float s_sc[2][256];
  __shared__ float s_cand[2][256];
  __shared__ int   s_tl[2][256];
  __shared__ int   s_wc[2][4];
  __shared__ float s_c4[2][4], s_r4[2][4], s_m4[2][4];
  __shared__ int   s_selI[2][KK];
  __shared__ float s_selV[2][KK];
  __shared__ float s_dS[2];
  __shared__ float s_xg[2][KK][HH + 4];

  // ---- phase 0: cs -> LDS, masks + counts, qb partials (both b's) ----
  const float csv0 = CS[(size_t)b0 * HH + tid];
  const float csv1 = CS[(size_t)b1 * HH + tid];
  s_cs[0][tid] = csv0;
  s_cs[1][tid] = csv1;
  const int m0 = (tid < TT) ? (VM[(size_t)b0 * TT + tid] != 0) : 0;
  const int m1 = (tid < TT) ? (VM[(size_t)b1 * TT + tid] != 0) : 0;
  {
    unsigned long long ba0 = __ballot(m0);
    unsigned long long ba1 = __ballot(m1);
    if (lane == 0) {
      s_c4[0][w] = (float)__popcll(ba0);
      s_c4[1][w] = (float)__popcll(ba1);
    }
  }
  const float ev = evec[tid];
  {
    float rq0 = wred_sum(csv0 * ev);
    float rq1 = wred_sum(csv1 * ev);
    if (lane == 0) { s_r4[0][w] = rq0; s_r4[1][w] = rq1; }
  }
  __syncthreads();

  const int cnt0 = (int)(s_c4[0][0] + s_c4[0][1] + s_c4[0][2] + s_c4[0][3]);
  const int cnt1 = (int)(s_c4[1][0] + s_c4[1][1] + s_c4[1][2] + s_c4[1][3]);
  const int hist0 = (m0 && (tid < cnt0 - 1)) ? 1 : 0;
  const int hist1 = (m1 && (tid < cnt1 - 1)) ? 1 : 0;
  const float fs = fsc[0];
  const float qb0 = (s_r4[0][0] + s_r4[0][1] + s_r4[0][2] + s_r4[0][3] + fs) * 0.0625f;
  const float qb1 = (s_r4[1][0] + s_r4[1][1] + s_r4[1][2] + s_r4[1][3] + fs) * 0.0625f;
  const unsigned long long bh0 = __ballot(hist0);
  const unsigned long long bh1 = __ballot(hist1);
  if (lane == 0) { s_wc[0][w] = __popcll(bh0); s_wc[1][w] = __popcll(bh1); }

  // ---- phase 1: QK rows for both b's; M2T read ONCE ----
  {
    float4 a0 = make_float4(0.f, 0.f, 0.f, 0.f);
    float4 a1 = make_float4(0.f, 0.f, 0.f, 0.f);
    const int l0 = w * 64;
    const float* mbase = M2T + (size_t)l0 * HH + lane * 4;
#pragma unroll 8
    for (int li = 0; li < 64; ++li) {
      const float c0 = s_cs[0][l0 + li];
      const float c1 = s_cs[1][l0 + li];
      const float4 m4 = *(const float4*)(mbase + (size_t)li * HH);
      a0.x += c0 * m4.x; a0.y += c0 * m4.y; a0.z += c0 * m4.z; a0.w += c0 * m4.w;
      a1.x += c1 * m4.x; a1.y += c1 * m4.y; a1.z += c1 * m4.z; a1.w += c1 * m4.w;
    }
    *(float4*)(&s_part[w][0][lane * 4]) = a0;
    *(float4*)(&s_part[w][1][lane * 4]) = a1;
  }
  __syncthreads();
  const int nh0 = s_wc[0][0] + s_wc[0][1] + s_wc[0][2] + s_wc[0][3];
  const int nh1 = s_wc[1][0] + s_wc[1][1] + s_wc[1][2] + s_wc[1][3];
  {
    int pre0 = 0, pre1 = 0;
#pragma unroll
    for (int i = 0; i < 4; ++i)
      if (i < w) { pre0 += s_wc[0][i]; pre1 += s_wc[1][i]; }
    const unsigned long long below = (1ull << lane) - 1ull;
    if (hist0) s_tl[0][pre0 + __popcll(bh0 & below)] = tid;
    if (hist1) s_tl[1][pre1 + __popcll(bh1 & below)] = tid;

    const float dv = M2T[(size_t)256 * HH + tid];
    s_qk[0][tid] = (s_part[0][0][tid] + s_part[1][0][tid] + s_part[2][0][tid] +
                    s_part[3][0][tid] + dv) * 0.0625f;
    s_qk[1][tid] = (s_part[0][1][tid] + s_part[1][1][tid] + s_part[2][1][tid] +
                    s_part[3][1][tid] + dv) * 0.0625f;
  }
  __syncthreads();

  // ---- phase 2: scores for compacted rows, both b's sequentially ----
#pragma unroll
  for (int nb = 0; nb < 2; ++nb) {
    const int bcur = b0 + nb;
    const int nh = nb ? nh1 : nh0;
    const float qb = nb ? qb1 : qb0;
    const float* xbase = X + (size_t)bcur * TT * HH + lane * 4;
    const float4 q4 = ((const float4*)s_qk[nb])[lane];
    int j = w;
    for (; j + 28 < nh; j += 32) {
      int tj[8];
#pragma unroll
      for (int u = 0; u < 8; ++u) tj[u] = s_tl[nb][j + 4 * u];
      float4 xv[8];
#pragma unroll
      for (int u = 0; u < 8; ++u)
        xv[u] = *(const float4*)(xbase + (size_t)tj[u] * HH);
      float pr[8];
#pragma unroll
      for (int u = 0; u < 8; ++u)
        pr[u] = xv[u].x * q4.x + xv[u].y * q4.y + xv[u].z * q4.z + xv[u].w * q4.w;
#pragma unroll
      for (int off = 32; off; off >>= 1)
#pragma unroll
        for (int u = 0; u < 8; ++u) pr[u] += __shfl_xor(pr[u], off);
      if (lane == 0) {
#pragma unroll
        for (int u = 0; u < 8; ++u) s_sc[nb][j + 4 * u] = pr[u] + qb;
      }
    }
    for (; j < nh; j += 4) {
      const int t = s_tl[nb][j];
      float4 xv = *(const float4*)(xbase + (size_t)t * HH);
      float p = xv.x * q4.x + xv.y * q4.y + xv.z * q4.z + xv.w * q4.w;
      p = wred_sum(p);
      if (lane == 0) s_sc[nb][j] = p + qb;
    }
  }
  __syncthreads();

  // ---- phase 3a: softmax over compacted entries (both b's) ----
  const int in0 = (tid < nh0), in1 = (tid < nh1);
  float v0 = in0 ? s_sc[0][tid] : -3.4e38f;
  float v1 = in1 ? s_sc[1][tid] : -3.4e38f;
  {
    float wm0 = wred_max(v0);
    float wm1 = wred_max(v1);
    if (lane == 0) { s_m4[0][w] = wm0; s_m4[1][w] = wm1; }
  }
  __syncthreads();
  const float mx0 = fmaxf(fmaxf(s_m4[0][0], s_m4[0][1]), fmaxf(s_m4[0][2], s_m4[0][3]));
  const float mx1 = fmaxf(fmaxf(s_m4[1][0], s_m4[1][1]), fmaxf(s_m4[1][2], s_m4[1][3]));
  float p0 = in0 ? expf(v0 - mx0) : 0.f;
  float p1 = in1 ? expf(v1 - mx1) : 0.f;
  {
    float ws0 = wred_sum(p0);
    float ws1 = wred_sum(p1);
    if (lane == 0) { s_r4[0][w] = ws0; s_r4[1][w] = ws1; }
  }
  __syncthreads();
  const float den0 = s_r4[0][0] + s_r4[0][1] + s_r4[0][2] + s_r4[0][3];
  const float den1 = s_r4[1][0] + s_r4[1][1] + s_r4[1][2] + s_r4[1][3];
  s_cand[0][tid] = in0 ? (p0 / den0) : -2.0f;
  s_cand[1][tid] = in1 ? (p1 / den1) : -2.0f;
  __syncthreads();

  // ---- phase 3b: top-8, wave 0 -> b0, wave 1 -> b1 (parallel) ----
  if (tid < 128) {
    const int nb = w;
    float lv[4]; int lt[4];
#pragma unroll
    for (int q = 0; q < 4; ++q) {
      int t = lane + 64 * q;
      lv[q] = s_cand[nb][t];
      lt[q] = t;
    }
    for (int r = 0; r < KK; ++r) {
      float bv = -2.5f; int bi = 1 << 30;
#pragma unroll
      for (int q = 0; q < 4; ++q)
        if (lv[q] > bv) { bv = lv[q]; bi = lt[q]; }
#pragma unroll
      for (int off = 32; off; off >>= 1) {
        float ov = __shfl_xor(bv, off);
        int   oi = __shfl_xor(bi, off);
        if (ov > bv || (ov == bv && oi < bi)) { bv = ov; bi = oi; }
      }
      if (lane == 0) {
        s_selV[nb][r] = bv;
        s_selI[nb][r] = (bv >= 0.f) ? s_tl[nb][bi] : 0;  // map back to original t
      }
#pragma unroll
      for (int q = 0; q < 4; ++q)
        if (lt[q] == bi) lv[q] = -3.0f;
    }
    if (lane == 0) {
      float S = 0.f;
#pragma unroll
      for (int r = 0; r < KK; ++r) S += fmaxf(s_selV[nb][r], 0.f);
      s_dS[nb] = fmaxf(S, 1.1920929e-07f);
    }
  }
  __syncthreads();

  // ---- phase 4: zero attn rows + gather 16 selected rows to LDS ----
  float* out_attn0 = out + (size_t)BB * HH + (size_t)b0 * TT;
  float* out_attn1 = out + (size_t)BB * HH + (size_t)b1 * TT;
  if (tid < TT) { out_attn0[tid] = 0.f; out_attn1[tid] = 0.f; }
#pragma unroll
  for (int it = 0; it < 4; ++it) {
    const int rr = it * 4 + w;
    const int nb = rr >> 3, r = rr & 7;
    const int t = s_selI[nb][r];                   // 0 when invalid (weight 0)
    const int c0 = lane * 4;
    *(float4*)(&s_xg[nb][r][c0]) =
        *(const float4*)(X + ((size_t)(b0 + nb) * TT + t) * HH + c0);
  }
  __syncthreads();

  if (tid < 2 * KK) {
    const int nb = tid >> 3, r = tid & 7;
    float vvv = s_selV[nb][r];
    int   bi  = s_selI[nb][r];
    float wf  = fmaxf(vvv, 0.f) / s_dS[nb];
    int ok = (vvv >= 0.f);
    float* oa = nb ? out_attn1 : out_attn0;
    if (ok) oa[bi] = wf;
    out[(size_t)BB * HH + (size_t)BB * TT + (size_t)(b0 + nb) * KK + r] =
        ok ? (float)bi : -1.0f;
  }

  // ---- phase 5: summary for both b's; Wv read ONCE per block ----
  // wave w owns output cols [w*64, w*64+64); lane = kk*16 + c16:
  // lane covers cols w*64 + c16*4 .. +3, k residue class kk (mod 4).
  {
    const int kk = lane >> 4, c16 = lane & 15;
    const float* wvbase = Wv + w * 64 + c16 * 4;
    float4 acc[2][KK];
#pragma unroll
    for (int nb = 0; nb < 2; ++nb)
#pragma unroll
      for (int r = 0; r < KK; ++r) acc[nb][r] = make_float4(0.f, 0.f, 0.f, 0.f);
#pragma unroll 2
    for (int kb = 0; kb < 64; ++kb) {
      const int k = kb * 4 + kk;
      const float4 wv4 = *(const float4*)(wvbase + (size_t)k * HH);
#pragma unroll
      for (int nb = 0; nb < 2; ++nb)
#pragma unroll
        for (int r = 0; r < KK; ++r) {
          const float xv = s_xg[nb][r][k];
          acc[nb][r].x += xv * wv4.x; acc[nb][r].y += xv * wv4.y;
          acc[nb][r].z += xv * wv4.z; acc[nb][r].w += xv * wv4.w;
        }
    }
    // combine the 4 k-residue groups (lanes c16, c16+16, c16+32, c16+48)
#pragma unroll
    for (int nb = 0; nb < 2; ++nb)
#pragma unroll
      for (int r = 0; r < KK; ++r) {
        acc[nb][r].x += __shfl_xor(acc[nb][r].x, 16);
        acc[nb][r].x += __shfl_xor(acc[nb][r].x, 32);
        acc[nb][r].y += __shfl_xor(acc[nb][r].y, 16);
        acc[nb][r].y += __shfl_xor(acc[nb][r].y, 32);
        acc[nb][r].z += __shfl_xor(acc[nb][r].z, 16);
        acc[nb][r].z += __shfl_xor(acc[nb][r].z, 32);
        acc[nb][r].w += __shfl_xor(acc[nb][r].w, 16);
        acc[nb][r].w += __shfl_xor(acc[nb][r].w, 32);
      }
    if (lane < 16) {
      const float4 bv4 = *(const float4*)(bvv + w * 64 + c16 * 4);
#pragma unroll
      for (int nb = 0; nb < 2; ++nb) {
        float4 res = make_float4(0.f, 0.f, 0.f, 0.f);
#pragma unroll
        for (int r = 0; r < KK; ++r) {
          const float wr = fmaxf(s_selV[nb][r], 0.f) / s_dS[nb];
          res.x += wr * fmaxf(acc[nb][r].x + bv4.x, 0.f);
          res.y += wr * fmaxf(acc[nb][r].y + bv4.y, 0.f);
          res.z += wr * fmaxf(acc[nb][r].z + bv4.z, 0.f);
          res.w += wr * fmaxf(acc[nb][r].w + bv4.w, 0.f);
        }
        *(float4*)(out + (size_t)(b0 + nb) * HH + w * 64 + c16 * 4) = res;
      }
    }
  }
}

// ---------------------------------------------------------------------------
extern "C" void kernel_launch(void* const* d_in, const int* in_sizes, int n_in,
                              void* d_out, int out_size, void* d_ws, size_t ws_size,
                              hipStream_t stream) {
  const float* cs  = (const float*)d_in[0];
  const float* X   = (const float*)d_in[1];
  const int*   vm  = (const int*)d_in[2];
  const float* Wq  = (const float*)d_in[3];
  const float* bq  = (const float*)d_in[4];
  const float* Wk  = (const float*)d_in[5];
  const float* bk  = (const float*)d_in[6];
  const float* Wv  = (const float*)d_in[7];
  const float* bvp = (const float*)d_in[8];
  float* out = (float*)d_out;
  float* ws  = (float*)d_ws;

  float* M2T  = ws + WS_M2T;
  float* evec = ws + WS_EVEC;
  float* fsc  = ws + WS_F;

  hipLaunchKernelGGL(prep_all, dim3(529), dim3(256), 0, stream,
                     Wq, bq, Wk, bk, M2T, evec, fsc);
  hipLaunchKernelGGL(fused_attn2, dim3(BB / 2), dim3(256), 0, stream,
                     cs, X, vm, M2T, evec, fsc, Wv, bvp, out);
}